// Round 10
// baseline (336.788 us; speedup 1.0000x reference)
//
#include <hip/hip_runtime.h>
#include <hip/hip_bf16.h>
#include <float.h>

#define NN 50000
#define NE 800000
#define DF 96
#define DI 32
#define CO 128          // conv out per layer
#define NG 500
#define HC 384
#define F1I 384
#define F1O 160
#define F2O 10
#define CAPLOG 7        // bucket capacity 128 = 8x Poisson(16) mean; P(overflow) ~ 1e-40

typedef unsigned int  u32;
typedef unsigned short u16;
typedef short bf16x8 __attribute__((ext_vector_type(8)));
typedef float f32x4  __attribute__((ext_vector_type(4)));

__device__ __forceinline__ u16 f2b(float f) {
    __hip_bfloat16 h = __float2bfloat16(f);
    return *reinterpret_cast<u16*>(&h);
}
__device__ __forceinline__ float b2f(u16 u) {
    return __uint_as_float(((u32)u) << 16);
}
__device__ __forceinline__ float blo(u32 u) { return __uint_as_float(u << 16); }
__device__ __forceinline__ float bhi(u32 u) { return __uint_as_float(u & 0xffff0000u); }

// ================= fused prep: zero cnt | starts | cast x | wt x3 | infow x3 =================
#define PB_CNT    196
#define PB_STARTS 196
#define PB_CAST   4688   // NN*96/4 = 1,200,000 threads
#define PB_WT0    96     // 256*96
#define PB_WT1    128    // 256*128
#define PB_WT2    128
#define PB_INFO   500
#define PREP_GRID (PB_CNT + PB_STARTS + PB_CAST + PB_WT0 + PB_WT1 + PB_WT2 + 3 * PB_INFO)

__global__ __launch_bounds__(256) void k_prep(
        const float* __restrict__ x, const int* __restrict__ batch, const float* __restrict__ info,
        const float* __restrict__ Wl0, const float* __restrict__ Wr0, const float* __restrict__ b0,
        const float* __restrict__ Wl1, const float* __restrict__ Wr1, const float* __restrict__ b1,
        const float* __restrict__ Wl2, const float* __restrict__ Wr2, const float* __restrict__ b2,
        int* __restrict__ cnt, int* __restrict__ start, u16* __restrict__ xb,
        u16* __restrict__ WT0, u16* __restrict__ WT1, u16* __restrict__ WT2,
        float* __restrict__ iQl0, float* __restrict__ iQr0,
        float* __restrict__ iQl1, float* __restrict__ iQr1,
        float* __restrict__ iQl2, float* __restrict__ iQr2) {
    int blk = blockIdx.x;
    int t = threadIdx.x;
    if (blk < PB_CNT) {
        int i = blk * 256 + t;
        if (i < NN) cnt[i] = 0;
        return;
    }
    blk -= PB_CNT;
    if (blk < PB_STARTS) {
        int i = blk * 256 + t;
        if (i >= NN) return;
        int b = batch[i];
        if (i == 0) { for (int g = 0; g <= b; ++g) start[g] = 0; }
        else {
            int p = batch[i - 1];
            if (p != b) for (int g = p + 1; g <= b; ++g) start[g] = i;
        }
        if (i == NN - 1) { for (int g = b + 1; g <= NG; ++g) start[g] = NN; }
        return;
    }
    blk -= PB_STARTS;
    if (blk < PB_CAST) {
        int tid = blk * 256 + t;
        if (tid >= NN * DF / 4) return;
        float4 v = *(const float4*)&x[tid * 4];
        ushort4 o;
        o.x = f2b(v.x); o.y = f2b(v.y); o.z = f2b(v.z); o.w = f2b(v.w);
        *(ushort4*)&xb[tid * 4] = o;
        return;
    }
    blk -= PB_CAST;
    if (blk < PB_WT0 + PB_WT1 + PB_WT2) {
        const float* Wl; const float* Wr; u16* WT; int K; int rel;
        if (blk < PB_WT0) { Wl = Wl0; Wr = Wr0; WT = WT0; K = 96;  rel = blk; }
        else if (blk < PB_WT0 + PB_WT1) { Wl = Wl1; Wr = Wr1; WT = WT1; K = 128; rel = blk - PB_WT0; }
        else { Wl = Wl2; Wr = Wr2; WT = WT2; K = 128; rel = blk - PB_WT0 - PB_WT1; }
        int tid = rel * 256 + t;
        if (tid >= 256 * K) return;
        int n = tid / K;
        int k = tid - n * K;
        float v = (n < CO) ? Wl[k * CO + n] : Wr[k * CO + (n - CO)];
        WT[tid] = f2b(v);
        return;
    }
    blk -= PB_WT0 + PB_WT1 + PB_WT2;
    {
        const float* Wl; const float* Wr; const float* bias; float* iQl; float* iQr; int Ktop; int g;
        if (blk < PB_INFO) { Wl = Wl0; Wr = Wr0; bias = b0; iQl = iQl0; iQr = iQr0; Ktop = 96;  g = blk; }
        else if (blk < 2 * PB_INFO) { Wl = Wl1; Wr = Wr1; bias = b1; iQl = iQl1; iQr = iQr1; Ktop = 128; g = blk - PB_INFO; }
        else { Wl = Wl2; Wr = Wr2; bias = b2; iQl = iQl2; iQr = iQr2; Ktop = 128; g = blk - 2 * PB_INFO; }
        int c = t & 127;
        int sel = t >> 7;
        const float* W = sel ? Wr : Wl;
        float a = sel ? bias[c] : 0.0f;
        for (int d = 0; d < DI; ++d)
            a += info[g * DI + d] * W[(Ktop + d) * CO + c];
        (sel ? iQr : iQl)[g * CO + c] = a;
    }
}

// ================= CSR pass 1: count + rank (coalesced rank store) =================
// 4 independent edges per thread for atomic-latency overlap.
__global__ __launch_bounds__(256) void k_hist(const int* __restrict__ dst,
                                              int* __restrict__ cnt, u16* __restrict__ rank) {
    int base = (blockIdx.x * 256 + threadIdx.x) * 4;
    if (base >= NE) return;
    int d0 = dst[base], d1 = dst[base + 1], d2 = dst[base + 2], d3 = dst[base + 3];
    int p0 = atomicAdd(&cnt[d0], 1);
    int p1 = atomicAdd(&cnt[d1], 1);
    int p2 = atomicAdd(&cnt[d2], 1);
    int p3 = atomicAdd(&cnt[d3], 1);
    ushort4 r;
    r.x = (u16)p0; r.y = (u16)p1; r.z = (u16)p2; r.w = (u16)p3;
    *(ushort4*)&rank[base] = r;
}

// ================= CSR pass 2: atomic-free scatter into fixed buckets =================
__global__ void k_fill(const int* __restrict__ src, const int* __restrict__ dst,
                       const u16* __restrict__ rank, u16* __restrict__ csr) {
    int e = blockIdx.x * blockDim.x + threadIdx.x;
    if (e >= NE) return;
    int p = rank[e];
    if (p < (1 << CAPLOG)) csr[(dst[e] << CAPLOG) + p] = (u16)src[e];
}

// ================= MFMA GEMM + fused combine =================
template<int K>
__global__ __launch_bounds__(256) void k_mfma(const u16* __restrict__ A,
                                              const u16* __restrict__ WTg,
                                              const int* __restrict__ batch,
                                              const float* __restrict__ iQl,
                                              const float* __restrict__ iQr,
                                              u16* __restrict__ zlp,
                                              u16* __restrict__ zq) {
    constexpr int PITCH = K + 8;
    __shared__ short lds[256 * PITCH];

    int tid  = threadIdx.x;
    int w    = tid >> 6;
    int lane = tid & 63;
    int quad = lane >> 4;
    int l15  = lane & 15;

    constexpr int CH = 256 * K / 8;
    const uint4* wp = (const uint4*)WTg;
    for (int c = tid; c < CH; c += 256) {
        int n  = c / (K / 8);
        int ko = (c - n * (K / 8)) * 8;
        *(uint4*)&lds[n * PITCH + ko] = wp[c];
    }
    __syncthreads();

    int i0 = blockIdx.x * 128 + w * 32;
    int r0 = i0 + l15;       if (r0 >= NN) r0 = NN - 1;
    int r1 = i0 + 16 + l15;  if (r1 >= NN) r1 = NN - 1;
    const short* A0 = (const short*)A + (size_t)r0 * K;
    const short* A1 = (const short*)A + (size_t)r1 * K;

    f32x4 acc[2][16];
#pragma unroll
    for (int rt = 0; rt < 2; ++rt)
#pragma unroll
        for (int ct = 0; ct < 16; ++ct)
            acc[rt][ct] = (f32x4){0.f, 0.f, 0.f, 0.f};

#pragma unroll
    for (int ks = 0; ks < K / 32; ++ks) {
        int ka = ks * 32 + quad * 8;
        bf16x8 a0 = *(const bf16x8*)(A0 + ka);
        bf16x8 a1 = *(const bf16x8*)(A1 + ka);
#pragma unroll
        for (int ct = 0; ct < 16; ++ct) {
            bf16x8 b = *(const bf16x8*)&lds[(ct * 16 + l15) * PITCH + ka];
            acc[0][ct] = __builtin_amdgcn_mfma_f32_16x16x32_bf16(a0, b, acc[0][ct], 0, 0, 0);
            acc[1][ct] = __builtin_amdgcn_mfma_f32_16x16x32_bf16(a1, b, acc[1][ct], 0, 0, 0);
        }
    }

#pragma unroll
    for (int rt = 0; rt < 2; ++rt) {
#pragma unroll
        for (int reg = 0; reg < 4; ++reg) {
            int row = i0 + rt * 16 + quad * 4 + reg;
            if (row < NN) {
                int b = batch[row];
                const float* ql = &iQl[b * CO];
                const float* qr = &iQr[b * CO];
                u16* lp = zlp + (size_t)row * CO;
                u16* qp = zq  + (size_t)row * CO;
#pragma unroll
                for (int ct = 0; ct < 8; ++ct) {
                    int col = ct * 16 + l15;
                    lp[col] = f2b(acc[rt][ct][reg] + ql[col]);
                }
#pragma unroll
                for (int ct = 8; ct < 16; ++ct) {
                    int col = ct * 16 + l15 - 128;
                    qp[col] = f2b(acc[rt][ct][reg] + qr[col]);
                }
            }
        }
    }
}

// ================= gather-mean: h = mean(zlp[nbrs]) + zq =================
// quarter-wave: 16 lanes x uint4 (16B) = one 256B row per load instruction;
// 4 chains -> 16 rows in flight; cross-quarter combine via shfl_xor(16/32).
// Neighbor list = fixed bucket csr[i<<CAPLOG .. +deg).
__device__ __forceinline__ void acc8(float* a, const uint4& u) {
    a[0] += blo(u.x); a[1] += bhi(u.x);
    a[2] += blo(u.y); a[3] += bhi(u.y);
    a[4] += blo(u.z); a[5] += bhi(u.z);
    a[6] += blo(u.w); a[7] += bhi(u.w);
}

__global__ __launch_bounds__(256) void k_gatherb(const u32* __restrict__ zlp, const u32* __restrict__ zq,
                                                 const int* __restrict__ cnt, const u16* __restrict__ csr,
                                                 u32* __restrict__ hout) {
    int wave = threadIdx.x >> 6;
    int lane = threadIdx.x & 63;
    int q    = lane >> 4;       // quarter 0..3
    int l16  = lane & 15;
    int i = blockIdx.x * 4 + wave;
    if (i >= NN) return;
    int deg = cnt[i];
    int degc = min(deg, 1 << CAPLOG);
    int s0 = i << CAPLOG;
    int s1 = s0 + degc;

    const uint4* Z = (const uint4*)zlp;   // row r -> Z[r*16 + l16]

    float a[8] = {0,0,0,0,0,0,0,0};
    float b[8] = {0,0,0,0,0,0,0,0};
    float c[8] = {0,0,0,0,0,0,0,0};
    float d[8] = {0,0,0,0,0,0,0,0};

    int e = s0;
    for (; e + 15 < s1; e += 16) {
        int n0 = csr[e + q];
        int n1 = csr[e + 4 + q];
        int n2 = csr[e + 8 + q];
        int n3 = csr[e + 12 + q];
        uint4 u0 = Z[(size_t)n0 * 16 + l16];
        uint4 u1 = Z[(size_t)n1 * 16 + l16];
        uint4 u2 = Z[(size_t)n2 * 16 + l16];
        uint4 u3 = Z[(size_t)n3 * 16 + l16];
        acc8(a, u0); acc8(b, u1); acc8(c, u2); acc8(d, u3);
    }
    for (; e < s1; e += 4) {
        if (e + q < s1) {
            int n0 = csr[e + q];
            uint4 u0 = Z[(size_t)n0 * 16 + l16];
            acc8(a, u0);
        }
    }
#pragma unroll
    for (int j = 0; j < 8; ++j) {
        a[j] += b[j] + c[j] + d[j];
        a[j] += __shfl_xor(a[j], 16);
        a[j] += __shfl_xor(a[j], 32);
    }
    if (q == 0) {
        float r = 1.0f / fmaxf((float)deg, 1.0f);
        uint4 qq = ((const uint4*)zq)[(size_t)i * 16 + l16];
        uint4 o;
        o.x = (u32)f2b(a[0] * r + blo(qq.x)) | ((u32)f2b(a[1] * r + bhi(qq.x)) << 16);
        o.y = (u32)f2b(a[2] * r + blo(qq.y)) | ((u32)f2b(a[3] * r + bhi(qq.y)) << 16);
        o.z = (u32)f2b(a[4] * r + blo(qq.z)) | ((u32)f2b(a[5] * r + bhi(qq.z)) << 16);
        o.w = (u32)f2b(a[6] * r + blo(qq.w)) | ((u32)f2b(a[7] * r + bhi(qq.w)) << 16);
        ((uint4*)hout)[(size_t)i * 16 + l16] = o;
    }
}

// ================= fused pool + FC head =================
__global__ __launch_bounds__(384) void k_poolfc(const u16* __restrict__ h1, const u16* __restrict__ h2,
                                                const u16* __restrict__ h3, const int* __restrict__ start,
                                                const float* __restrict__ W1, const float* __restrict__ b1,
                                                const float* __restrict__ W2, const float* __restrict__ b2,
                                                float* __restrict__ out) {
    __shared__ float s_g[F1I];
    __shared__ float s_z[F1O];
    int gr = blockIdx.x;
    int c  = threadIdx.x;
    int sel = c >> 7;
    int cc  = c & 127;
    const u16* hb = (sel == 0) ? h1 : (sel == 1) ? h2 : h3;
    int s = start[gr], e = start[gr + 1];
    float m0 = -FLT_MAX, m1 = -FLT_MAX;
    int n = s;
    for (; n + 1 < e; n += 2) {
        m0 = fmaxf(m0, b2f(hb[n * 128 + cc]));
        m1 = fmaxf(m1, b2f(hb[(n + 1) * 128 + cc]));
    }
    if (n < e) m0 = fmaxf(m0, b2f(hb[n * 128 + cc]));
    s_g[c] = fmaxf(m0, m1);
    __syncthreads();
    if (c < F1O) {
        float acc = b1[c];
        for (int k = 0; k < F1I; ++k) acc += s_g[k] * W1[k * F1O + c];
        s_z[c] = fmaxf(acc, 0.0f);
    }
    __syncthreads();
    if (c < F2O) {
        float a = b2[c];
        for (int k = 0; k < F1O; ++k) a += s_z[k] * W2[k * F2O + c];
        out[gr * F2O + c] = a;
    }
}

extern "C" void kernel_launch(void* const* d_in, const int* in_sizes, int n_in,
                              void* d_out, int out_size, void* d_ws, size_t ws_size,
                              hipStream_t stream) {
    const float* x     = (const float*)d_in[0];
    const int*   eidx  = (const int*)d_in[1];
    const int*   batch = (const int*)d_in[2];
    const float* info  = (const float*)d_in[3];
    const float* Wl0 = (const float*)d_in[4];
    const float* Wr0 = (const float*)d_in[5];
    const float* b0  = (const float*)d_in[6];
    const float* Wl1 = (const float*)d_in[7];
    const float* Wr1 = (const float*)d_in[8];
    const float* b1  = (const float*)d_in[9];
    const float* Wl2 = (const float*)d_in[10];
    const float* Wr2 = (const float*)d_in[11];
    const float* b2  = (const float*)d_in[12];
    const float* Wfc1  = (const float*)d_in[13];
    const float* bfc1  = (const float*)d_in[14];
    const float* Wfc2  = (const float*)d_in[15];
    const float* bfc2  = (const float*)d_in[16];
    float* out = (float*)d_out;

    const int* src = eidx;
    const int* dst = eidx + NE;

    // workspace layout (byte offsets, 16B-aligned)
    char* W = (char*)d_ws;
    u16* xb     = (u16*)(W + 0);             // 50000*96 bf16
    u16* h1     = (u16*)(W + 9600000);       // 50000*128 bf16 each
    u16* h2     = (u16*)(W + 22400000);
    u16* h3     = (u16*)(W + 35200000);
    u16* zlp    = (u16*)(W + 48000000);      // 50000*128 bf16
    u16* zq     = (u16*)(W + 60800000);
    u16* WT0    = (u16*)(W + 73600000);      // 256*96
    u16* WT1    = (u16*)(W + 73649152);      // 256*128
    u16* WT2    = (u16*)(W + 73714688);
    float* iQl0 = (float*)(W + 73780224);    // 500*128 f32 each
    float* iQr0 = (float*)(W + 74036224);
    float* iQl1 = (float*)(W + 74292224);
    float* iQr1 = (float*)(W + 74548224);
    float* iQl2 = (float*)(W + 74804224);
    float* iQr2 = (float*)(W + 75060224);
    int* start  = (int*)(W + 75316224);      // NG+1
    int* cnt    = (int*)(W + 75318272);      // NN
    u16* csr    = (u16*)(W + 75518336);      // NN*128 u16 buckets = 12.8 MB
    u16* rank   = (u16*)(W + 88318336);      // NE u16

    // ---- fused prep (zero cnt | starts | cast | wt | infow) ----
    k_prep<<<PREP_GRID, 256, 0, stream>>>(x, batch, info,
        Wl0, Wr0, b0, Wl1, Wr1, b1, Wl2, Wr2, b2,
        cnt, start, xb, WT0, WT1, WT2, iQl0, iQr0, iQl1, iQr1, iQl2, iQr2);

    // ---- CSR: count+rank, then atomic-free scatter ----
    k_hist<<<(NE / 4 + 255) / 256, 256, 0, stream>>>(dst, cnt, rank);
    k_fill<<<(NE + 255) / 256, 256, 0, stream>>>(src, dst, rank, csr);

    const int gGemm = (NN + 127) / 128;
    const int gGath = (NN + 3) / 4;

    // ---- layer 0 ----
    k_mfma<96><<<gGemm, 256, 0, stream>>>(xb, WT0, batch, iQl0, iQr0, zlp, zq);
    k_gatherb<<<gGath, 256, 0, stream>>>((const u32*)zlp, (const u32*)zq, cnt, csr, (u32*)h1);

    // ---- layer 1 ----
    k_mfma<128><<<gGemm, 256, 0, stream>>>(h1, WT1, batch, iQl1, iQr1, zlp, zq);
    k_gatherb<<<gGath, 256, 0, stream>>>((const u32*)zlp, (const u32*)zq, cnt, csr, (u32*)h2);

    // ---- layer 2 ----
    k_mfma<128><<<gGemm, 256, 0, stream>>>(h2, WT2, batch, iQl2, iQr2, zlp, zq);
    k_gatherb<<<gGath, 256, 0, stream>>>((const u32*)zlp, (const u32*)zq, cnt, csr, (u32*)h3);

    // ---- fused pool + head ----
    k_poolfc<<<NG, 384, 0, stream>>>(h1, h2, h3, start, Wfc1, bfc1, Wfc2, bfc2, out);
}

// Round 11
// 324.005 us; speedup vs baseline: 1.0395x; 1.0395x over previous
//
#include <hip/hip_runtime.h>
#include <hip/hip_bf16.h>
#include <float.h>

#define NN 50000
#define NE 800000
#define DF 96
#define DI 32
#define CO 128          // conv out per layer
#define NG 500
#define HC 384
#define F1I 384
#define F1O 160
#define F2O 10
#define CAPLOG 7        // bucket capacity 128 = 8x Poisson(16) mean; P(overflow) ~ 1e-40

typedef unsigned int  u32;
typedef unsigned short u16;
typedef short bf16x8 __attribute__((ext_vector_type(8)));
typedef float f32x4  __attribute__((ext_vector_type(4)));

__device__ __forceinline__ u16 f2b(float f) {
    __hip_bfloat16 h = __float2bfloat16(f);
    return *reinterpret_cast<u16*>(&h);
}
__device__ __forceinline__ float b2f(u16 u) {
    return __uint_as_float(((u32)u) << 16);
}
__device__ __forceinline__ float blo(u32 u) { return __uint_as_float(u << 16); }
__device__ __forceinline__ float bhi(u32 u) { return __uint_as_float(u & 0xffff0000u); }

// ================= fused prep: histfill | starts | cast x | wt x3 | infow x3 =================
// Edge blocks FIRST so the latency-bound histfill waves start earliest and overlap
// with the bandwidth/compute prep sections. cnt is zeroed by a preceding memset.
#define PB_EDGE   782    // NE/4/256
#define PB_STARTS 196
#define PB_CAST   4688   // NN*96/4 = 1,200,000 threads
#define PB_WT0    96     // 256*96
#define PB_WT1    128    // 256*128
#define PB_WT2    128
#define PB_INFO   500
#define PREP_GRID (PB_EDGE + PB_STARTS + PB_CAST + PB_WT0 + PB_WT1 + PB_WT2 + 3 * PB_INFO)

__global__ __launch_bounds__(256) void k_prep(
        const float* __restrict__ x, const int* __restrict__ batch, const float* __restrict__ info,
        const int* __restrict__ src, const int* __restrict__ dst,
        const float* __restrict__ Wl0, const float* __restrict__ Wr0, const float* __restrict__ b0,
        const float* __restrict__ Wl1, const float* __restrict__ Wr1, const float* __restrict__ b1,
        const float* __restrict__ Wl2, const float* __restrict__ Wr2, const float* __restrict__ b2,
        int* __restrict__ cnt, u16* __restrict__ csr,
        int* __restrict__ start, u16* __restrict__ xb,
        u16* __restrict__ WT0, u16* __restrict__ WT1, u16* __restrict__ WT2,
        float* __restrict__ iQl0, float* __restrict__ iQr0,
        float* __restrict__ iQl1, float* __restrict__ iQr1,
        float* __restrict__ iQl2, float* __restrict__ iQr2) {
    int blk = blockIdx.x;
    int t = threadIdx.x;
    if (blk < PB_EDGE) {                                  // single-pass CSR histfill
        int base = (blk * 256 + t) * 4;
        if (base < NE) {
            int4 dv = *(const int4*)&dst[base];
            int4 sv = *(const int4*)&src[base];
            int p0 = atomicAdd(&cnt[dv.x], 1);
            int p1 = atomicAdd(&cnt[dv.y], 1);
            int p2 = atomicAdd(&cnt[dv.z], 1);
            int p3 = atomicAdd(&cnt[dv.w], 1);
            if (p0 < (1 << CAPLOG)) csr[(dv.x << CAPLOG) + p0] = (u16)sv.x;
            if (p1 < (1 << CAPLOG)) csr[(dv.y << CAPLOG) + p1] = (u16)sv.y;
            if (p2 < (1 << CAPLOG)) csr[(dv.z << CAPLOG) + p2] = (u16)sv.z;
            if (p3 < (1 << CAPLOG)) csr[(dv.w << CAPLOG) + p3] = (u16)sv.w;
        }
        return;
    }
    blk -= PB_EDGE;
    if (blk < PB_STARTS) {
        int i = blk * 256 + t;
        if (i >= NN) return;
        int b = batch[i];
        if (i == 0) { for (int g = 0; g <= b; ++g) start[g] = 0; }
        else {
            int p = batch[i - 1];
            if (p != b) for (int g = p + 1; g <= b; ++g) start[g] = i;
        }
        if (i == NN - 1) { for (int g = b + 1; g <= NG; ++g) start[g] = NN; }
        return;
    }
    blk -= PB_STARTS;
    if (blk < PB_CAST) {
        int tid = blk * 256 + t;
        if (tid >= NN * DF / 4) return;
        float4 v = *(const float4*)&x[tid * 4];
        ushort4 o;
        o.x = f2b(v.x); o.y = f2b(v.y); o.z = f2b(v.z); o.w = f2b(v.w);
        *(ushort4*)&xb[tid * 4] = o;
        return;
    }
    blk -= PB_CAST;
    if (blk < PB_WT0 + PB_WT1 + PB_WT2) {
        const float* Wl; const float* Wr; u16* WT; int K; int rel;
        if (blk < PB_WT0) { Wl = Wl0; Wr = Wr0; WT = WT0; K = 96;  rel = blk; }
        else if (blk < PB_WT0 + PB_WT1) { Wl = Wl1; Wr = Wr1; WT = WT1; K = 128; rel = blk - PB_WT0; }
        else { Wl = Wl2; Wr = Wr2; WT = WT2; K = 128; rel = blk - PB_WT0 - PB_WT1; }
        int tid = rel * 256 + t;
        if (tid >= 256 * K) return;
        int n = tid / K;
        int k = tid - n * K;
        float v = (n < CO) ? Wl[k * CO + n] : Wr[k * CO + (n - CO)];
        WT[tid] = f2b(v);
        return;
    }
    blk -= PB_WT0 + PB_WT1 + PB_WT2;
    {
        const float* Wl; const float* Wr; const float* bias; float* iQl; float* iQr; int Ktop; int g;
        if (blk < PB_INFO) { Wl = Wl0; Wr = Wr0; bias = b0; iQl = iQl0; iQr = iQr0; Ktop = 96;  g = blk; }
        else if (blk < 2 * PB_INFO) { Wl = Wl1; Wr = Wr1; bias = b1; iQl = iQl1; iQr = iQr1; Ktop = 128; g = blk - PB_INFO; }
        else { Wl = Wl2; Wr = Wr2; bias = b2; iQl = iQl2; iQr = iQr2; Ktop = 128; g = blk - 2 * PB_INFO; }
        int c = t & 127;
        int sel = t >> 7;
        const float* W = sel ? Wr : Wl;
        float a = sel ? bias[c] : 0.0f;
        for (int d = 0; d < DI; ++d)
            a += info[g * DI + d] * W[(Ktop + d) * CO + c];
        (sel ? iQr : iQl)[g * CO + c] = a;
    }
}

// ================= MFMA GEMM + fused combine =================
template<int K>
__global__ __launch_bounds__(256) void k_mfma(const u16* __restrict__ A,
                                              const u16* __restrict__ WTg,
                                              const int* __restrict__ batch,
                                              const float* __restrict__ iQl,
                                              const float* __restrict__ iQr,
                                              u16* __restrict__ zlp,
                                              u16* __restrict__ zq) {
    constexpr int PITCH = K + 8;
    __shared__ short lds[256 * PITCH];

    int tid  = threadIdx.x;
    int w    = tid >> 6;
    int lane = tid & 63;
    int quad = lane >> 4;
    int l15  = lane & 15;

    constexpr int CH = 256 * K / 8;
    const uint4* wp = (const uint4*)WTg;
    for (int c = tid; c < CH; c += 256) {
        int n  = c / (K / 8);
        int ko = (c - n * (K / 8)) * 8;
        *(uint4*)&lds[n * PITCH + ko] = wp[c];
    }
    __syncthreads();

    int i0 = blockIdx.x * 128 + w * 32;
    int r0 = i0 + l15;       if (r0 >= NN) r0 = NN - 1;
    int r1 = i0 + 16 + l15;  if (r1 >= NN) r1 = NN - 1;
    const short* A0 = (const short*)A + (size_t)r0 * K;
    const short* A1 = (const short*)A + (size_t)r1 * K;

    f32x4 acc[2][16];
#pragma unroll
    for (int rt = 0; rt < 2; ++rt)
#pragma unroll
        for (int ct = 0; ct < 16; ++ct)
            acc[rt][ct] = (f32x4){0.f, 0.f, 0.f, 0.f};

#pragma unroll
    for (int ks = 0; ks < K / 32; ++ks) {
        int ka = ks * 32 + quad * 8;
        bf16x8 a0 = *(const bf16x8*)(A0 + ka);
        bf16x8 a1 = *(const bf16x8*)(A1 + ka);
#pragma unroll
        for (int ct = 0; ct < 16; ++ct) {
            bf16x8 b = *(const bf16x8*)&lds[(ct * 16 + l15) * PITCH + ka];
            acc[0][ct] = __builtin_amdgcn_mfma_f32_16x16x32_bf16(a0, b, acc[0][ct], 0, 0, 0);
            acc[1][ct] = __builtin_amdgcn_mfma_f32_16x16x32_bf16(a1, b, acc[1][ct], 0, 0, 0);
        }
    }

#pragma unroll
    for (int rt = 0; rt < 2; ++rt) {
#pragma unroll
        for (int reg = 0; reg < 4; ++reg) {
            int row = i0 + rt * 16 + quad * 4 + reg;
            if (row < NN) {
                int b = batch[row];
                const float* ql = &iQl[b * CO];
                const float* qr = &iQr[b * CO];
                u16* lp = zlp + (size_t)row * CO;
                u16* qp = zq  + (size_t)row * CO;
#pragma unroll
                for (int ct = 0; ct < 8; ++ct) {
                    int col = ct * 16 + l15;
                    lp[col] = f2b(acc[rt][ct][reg] + ql[col]);
                }
#pragma unroll
                for (int ct = 8; ct < 16; ++ct) {
                    int col = ct * 16 + l15 - 128;
                    qp[col] = f2b(acc[rt][ct][reg] + qr[col]);
                }
            }
        }
    }
}

// ================= gather-mean: h = mean(zlp[nbrs]) + zq =================
__device__ __forceinline__ void acc8(float* a, const uint4& u) {
    a[0] += blo(u.x); a[1] += bhi(u.x);
    a[2] += blo(u.y); a[3] += bhi(u.y);
    a[4] += blo(u.z); a[5] += bhi(u.z);
    a[6] += blo(u.w); a[7] += bhi(u.w);
}

__global__ __launch_bounds__(256) void k_gatherb(const u32* __restrict__ zlp, const u32* __restrict__ zq,
                                                 const int* __restrict__ cnt, const u16* __restrict__ csr,
                                                 u32* __restrict__ hout) {
    int wave = threadIdx.x >> 6;
    int lane = threadIdx.x & 63;
    int q    = lane >> 4;       // quarter 0..3
    int l16  = lane & 15;
    int i = blockIdx.x * 4 + wave;
    if (i >= NN) return;
    int deg = cnt[i];
    int degc = min(deg, 1 << CAPLOG);
    int s0 = i << CAPLOG;
    int s1 = s0 + degc;

    const uint4* Z = (const uint4*)zlp;   // row r -> Z[r*16 + l16]

    float a[8] = {0,0,0,0,0,0,0,0};
    float b[8] = {0,0,0,0,0,0,0,0};
    float c[8] = {0,0,0,0,0,0,0,0};
    float d[8] = {0,0,0,0,0,0,0,0};

    int e = s0;
    for (; e + 15 < s1; e += 16) {
        int n0 = csr[e + q];
        int n1 = csr[e + 4 + q];
        int n2 = csr[e + 8 + q];
        int n3 = csr[e + 12 + q];
        uint4 u0 = Z[(size_t)n0 * 16 + l16];
        uint4 u1 = Z[(size_t)n1 * 16 + l16];
        uint4 u2 = Z[(size_t)n2 * 16 + l16];
        uint4 u3 = Z[(size_t)n3 * 16 + l16];
        acc8(a, u0); acc8(b, u1); acc8(c, u2); acc8(d, u3);
    }
    for (; e < s1; e += 4) {
        if (e + q < s1) {
            int n0 = csr[e + q];
            uint4 u0 = Z[(size_t)n0 * 16 + l16];
            acc8(a, u0);
        }
    }
#pragma unroll
    for (int j = 0; j < 8; ++j) {
        a[j] += b[j] + c[j] + d[j];
        a[j] += __shfl_xor(a[j], 16);
        a[j] += __shfl_xor(a[j], 32);
    }
    if (q == 0) {
        float r = 1.0f / fmaxf((float)deg, 1.0f);
        uint4 qq = ((const uint4*)zq)[(size_t)i * 16 + l16];
        uint4 o;
        o.x = (u32)f2b(a[0] * r + blo(qq.x)) | ((u32)f2b(a[1] * r + bhi(qq.x)) << 16);
        o.y = (u32)f2b(a[2] * r + blo(qq.y)) | ((u32)f2b(a[3] * r + bhi(qq.y)) << 16);
        o.z = (u32)f2b(a[4] * r + blo(qq.z)) | ((u32)f2b(a[5] * r + bhi(qq.z)) << 16);
        o.w = (u32)f2b(a[6] * r + blo(qq.w)) | ((u32)f2b(a[7] * r + bhi(qq.w)) << 16);
        ((uint4*)hout)[(size_t)i * 16 + l16] = o;
    }
}

// ================= fused pool + FC head =================
// 6 waves = 3 buffers x 2 node-halves; lane covers one u32 (2 bf16 cols) so a wave
// reads a full 256B row per instruction; 4 independent max chains per wave.
__global__ __launch_bounds__(384) void k_poolfc(const u32* __restrict__ h1, const u32* __restrict__ h2,
                                                const u32* __restrict__ h3, const int* __restrict__ start,
                                                const float* __restrict__ W1, const float* __restrict__ b1,
                                                const float* __restrict__ W2, const float* __restrict__ b2,
                                                float* __restrict__ out) {
    __shared__ float s_part[6][128];
    __shared__ float s_g[F1I];
    __shared__ float s_z[F1O];
    int gr = blockIdx.x;
    int t  = threadIdx.x;
    int w    = t >> 6;          // 0..5
    int lane = t & 63;
    int buf  = w % 3;
    int half = w / 3;
    const u32* hb = (buf == 0) ? h1 : (buf == 1) ? h2 : h3;
    int s = start[gr], e = start[gr + 1];
    int mid = (s + e) >> 1;
    int n0 = half ? mid : s;
    int n1 = half ? e : mid;

    float mlo[4], mhi[4];
#pragma unroll
    for (int j = 0; j < 4; ++j) { mlo[j] = -FLT_MAX; mhi[j] = -FLT_MAX; }
    int n = n0;
    for (; n + 3 < n1; n += 4) {
        u32 v0 = hb[(size_t)(n + 0) * 64 + lane];
        u32 v1 = hb[(size_t)(n + 1) * 64 + lane];
        u32 v2 = hb[(size_t)(n + 2) * 64 + lane];
        u32 v3 = hb[(size_t)(n + 3) * 64 + lane];
        mlo[0] = fmaxf(mlo[0], blo(v0)); mhi[0] = fmaxf(mhi[0], bhi(v0));
        mlo[1] = fmaxf(mlo[1], blo(v1)); mhi[1] = fmaxf(mhi[1], bhi(v1));
        mlo[2] = fmaxf(mlo[2], blo(v2)); mhi[2] = fmaxf(mhi[2], bhi(v2));
        mlo[3] = fmaxf(mlo[3], blo(v3)); mhi[3] = fmaxf(mhi[3], bhi(v3));
    }
    for (; n < n1; ++n) {
        u32 v0 = hb[(size_t)n * 64 + lane];
        mlo[0] = fmaxf(mlo[0], blo(v0)); mhi[0] = fmaxf(mhi[0], bhi(v0));
    }
    float lo = fmaxf(fmaxf(mlo[0], mlo[1]), fmaxf(mlo[2], mlo[3]));
    float hi = fmaxf(fmaxf(mhi[0], mhi[1]), fmaxf(mhi[2], mhi[3]));
    s_part[w][2 * lane]     = lo;
    s_part[w][2 * lane + 1] = hi;
    __syncthreads();
    {   // combine the two node-halves; t in [0,384) maps to hcat column
        int buf2 = t >> 7, cc = t & 127;
        s_g[t] = fmaxf(s_part[buf2][cc], s_part[buf2 + 3][cc]);
    }
    __syncthreads();
    if (t < F1O) {
        float acc = b1[t];
        for (int k = 0; k < F1I; ++k) acc += s_g[k] * W1[k * F1O + t];
        s_z[t] = fmaxf(acc, 0.0f);
    }
    __syncthreads();
    if (t < F2O) {
        float a = b2[t];
        for (int k = 0; k < F1O; ++k) a += s_z[k] * W2[k * F2O + t];
        out[gr * F2O + t] = a;
    }
}

extern "C" void kernel_launch(void* const* d_in, const int* in_sizes, int n_in,
                              void* d_out, int out_size, void* d_ws, size_t ws_size,
                              hipStream_t stream) {
    const float* x     = (const float*)d_in[0];
    const int*   eidx  = (const int*)d_in[1];
    const int*   batch = (const int*)d_in[2];
    const float* info  = (const float*)d_in[3];
    const float* Wl0 = (const float*)d_in[4];
    const float* Wr0 = (const float*)d_in[5];
    const float* b0  = (const float*)d_in[6];
    const float* Wl1 = (const float*)d_in[7];
    const float* Wr1 = (const float*)d_in[8];
    const float* b1  = (const float*)d_in[9];
    const float* Wl2 = (const float*)d_in[10];
    const float* Wr2 = (const float*)d_in[11];
    const float* b2  = (const float*)d_in[12];
    const float* Wfc1  = (const float*)d_in[13];
    const float* bfc1  = (const float*)d_in[14];
    const float* Wfc2  = (const float*)d_in[15];
    const float* bfc2  = (const float*)d_in[16];
    float* out = (float*)d_out;

    const int* src = eidx;
    const int* dst = eidx + NE;

    // workspace layout (byte offsets, 16B-aligned)
    char* W = (char*)d_ws;
    u16* xb     = (u16*)(W + 0);             // 50000*96 bf16
    u16* h1     = (u16*)(W + 9600000);       // 50000*128 bf16 each
    u16* h2     = (u16*)(W + 22400000);
    u16* h3     = (u16*)(W + 35200000);
    u16* zlp    = (u16*)(W + 48000000);      // 50000*128 bf16
    u16* zq     = (u16*)(W + 60800000);
    u16* WT0    = (u16*)(W + 73600000);      // 256*96
    u16* WT1    = (u16*)(W + 73649152);      // 256*128
    u16* WT2    = (u16*)(W + 73714688);
    float* iQl0 = (float*)(W + 73780224);    // 500*128 f32 each
    float* iQr0 = (float*)(W + 74036224);
    float* iQl1 = (float*)(W + 74292224);
    float* iQr1 = (float*)(W + 74548224);
    float* iQl2 = (float*)(W + 74804224);
    float* iQr2 = (float*)(W + 75060224);
    int* start  = (int*)(W + 75316224);      // NG+1
    int* cnt    = (int*)(W + 75318272);      // NN
    u16* csr    = (u16*)(W + 75518336);      // NN*128 u16 buckets = 12.8 MB

    // ---- zero cnt (stream-ordered before the fused prep's atomics) ----
    hipMemsetAsync(cnt, 0, NN * sizeof(int), stream);

    // ---- fused prep: histfill | starts | cast | wt | infow ----
    k_prep<<<PREP_GRID, 256, 0, stream>>>(x, batch, info, src, dst,
        Wl0, Wr0, b0, Wl1, Wr1, b1, Wl2, Wr2, b2,
        cnt, csr, start, xb, WT0, WT1, WT2, iQl0, iQr0, iQl1, iQr1, iQl2, iQr2);

    const int gGemm = (NN + 127) / 128;
    const int gGath = (NN + 3) / 4;

    // ---- layer 0 ----
    k_mfma<96><<<gGemm, 256, 0, stream>>>(xb, WT0, batch, iQl0, iQr0, zlp, zq);
    k_gatherb<<<gGath, 256, 0, stream>>>((const u32*)zlp, (const u32*)zq, cnt, csr, (u32*)h1);

    // ---- layer 1 ----
    k_mfma<128><<<gGemm, 256, 0, stream>>>(h1, WT1, batch, iQl1, iQr1, zlp, zq);
    k_gatherb<<<gGath, 256, 0, stream>>>((const u32*)zlp, (const u32*)zq, cnt, csr, (u32*)h2);

    // ---- layer 2 ----
    k_mfma<128><<<gGemm, 256, 0, stream>>>(h2, WT2, batch, iQl2, iQr2, zlp, zq);
    k_gatherb<<<gGath, 256, 0, stream>>>((const u32*)zlp, (const u32*)zq, cnt, csr, (u32*)h3);

    // ---- fused pool + head ----
    k_poolfc<<<NG, 384, 0, stream>>>((const u32*)h1, (const u32*)h2, (const u32*)h3, start,
                                     Wfc1, bfc1, Wfc2, bfc2, out);
}

// Round 12
// 300.499 us; speedup vs baseline: 1.1208x; 1.0782x over previous
//
#include <hip/hip_runtime.h>
#include <hip/hip_bf16.h>
#include <float.h>

#define NN 50000
#define NE 800000
#define DF 96
#define DI 32
#define CO 128          // conv out per layer
#define NG 500
#define HC 384
#define F1I 384
#define F1O 160
#define F2O 10
#define CAPLOG 7        // bucket capacity 128; max observed deg ~45
#define NRANGE 196      // ranges of 256 nodes (dst>>8), 50000>>8 = 195
#define EPB 3125        // edges per binA block (256 blocks)
#define RCAPLOG 13      // ebin region capacity 8192 per range (mean 4082)

typedef unsigned int  u32;
typedef unsigned short u16;
typedef short bf16x8 __attribute__((ext_vector_type(8)));
typedef float f32x4  __attribute__((ext_vector_type(4)));

__device__ __forceinline__ u16 f2b(float f) {
    __hip_bfloat16 h = __float2bfloat16(f);
    return *reinterpret_cast<u16*>(&h);
}
__device__ __forceinline__ float b2f(u16 u) {
    return __uint_as_float(((u32)u) << 16);
}
__device__ __forceinline__ float blo(u32 u) { return __uint_as_float(u << 16); }
__device__ __forceinline__ float bhi(u32 u) { return __uint_as_float(u & 0xffff0000u); }

// ================= fused prep: binA | starts | cast x | wt x3 | infow x3 =================
#define PB_BIN    256
#define PB_STARTS 196
#define PB_CAST   4688   // NN*96/4
#define PB_WT0    96
#define PB_WT1    128
#define PB_WT2    128
#define PB_INFO   500
#define PREP_GRID (PB_BIN + PB_STARTS + PB_CAST + PB_WT0 + PB_WT1 + PB_WT2 + 3 * PB_INFO)

__global__ __launch_bounds__(256) void k_prep(
        const float* __restrict__ x, const int* __restrict__ batch, const float* __restrict__ info,
        const int* __restrict__ src, const int* __restrict__ dst,
        const float* __restrict__ Wl0, const float* __restrict__ Wr0, const float* __restrict__ b0,
        const float* __restrict__ Wl1, const float* __restrict__ Wr1, const float* __restrict__ b1,
        const float* __restrict__ Wl2, const float* __restrict__ Wr2, const float* __restrict__ b2,
        int* __restrict__ grescnt, u32* __restrict__ ebin,
        int* __restrict__ start, u16* __restrict__ xb,
        u16* __restrict__ WT0, u16* __restrict__ WT1, u16* __restrict__ WT2,
        float* __restrict__ iQl0, float* __restrict__ iQr0,
        float* __restrict__ iQl1, float* __restrict__ iQr1,
        float* __restrict__ iQl2, float* __restrict__ iQr2) {
    __shared__ u32 pairs[EPB];
    __shared__ int lcnt[256];
    int blk = blockIdx.x;
    int t = threadIdx.x;
    if (blk < PB_BIN) {                                   // binA: range-bucket edges
        int base = blk * EPB;
        lcnt[t] = 0;
        __syncthreads();
        for (int j = t; j < EPB; j += 256) {
            int e = base + j;
            int d = dst[e];
            int s = src[e];
            pairs[j] = ((u32)(d & 255) << 24) | ((u32)(d >> 8) << 16) | (u32)s;
            atomicAdd(&lcnt[d >> 8], 1);
        }
        __syncthreads();
        int myCnt = lcnt[t];
        int myBase = atomicAdd(&grescnt[t * 16], myCnt);  // padded counters: 1 per 64B line
        __syncthreads();
        lcnt[t] = myBase;
        __syncthreads();
        for (int j = t; j < EPB; j += 256) {
            u32 p = pairs[j];
            int r = (p >> 16) & 255;
            int pos = atomicAdd(&lcnt[r], 1);
            if (pos < (1 << RCAPLOG)) ebin[(r << RCAPLOG) + pos] = p;
        }
        return;
    }
    blk -= PB_BIN;
    if (blk < PB_STARTS) {
        int i = blk * 256 + t;
        if (i >= NN) return;
        int b = batch[i];
        if (i == 0) { for (int g = 0; g <= b; ++g) start[g] = 0; }
        else {
            int p = batch[i - 1];
            if (p != b) for (int g = p + 1; g <= b; ++g) start[g] = i;
        }
        if (i == NN - 1) { for (int g = b + 1; g <= NG; ++g) start[g] = NN; }
        return;
    }
    blk -= PB_STARTS;
    if (blk < PB_CAST) {
        int tid = blk * 256 + t;
        if (tid >= NN * DF / 4) return;
        float4 v = *(const float4*)&x[tid * 4];
        ushort4 o;
        o.x = f2b(v.x); o.y = f2b(v.y); o.z = f2b(v.z); o.w = f2b(v.w);
        *(ushort4*)&xb[tid * 4] = o;
        return;
    }
    blk -= PB_CAST;
    if (blk < PB_WT0 + PB_WT1 + PB_WT2) {
        const float* Wl; const float* Wr; u16* WT; int K; int rel;
        if (blk < PB_WT0) { Wl = Wl0; Wr = Wr0; WT = WT0; K = 96;  rel = blk; }
        else if (blk < PB_WT0 + PB_WT1) { Wl = Wl1; Wr = Wr1; WT = WT1; K = 128; rel = blk - PB_WT0; }
        else { Wl = Wl2; Wr = Wr2; WT = WT2; K = 128; rel = blk - PB_WT0 - PB_WT1; }
        int tid = rel * 256 + t;
        if (tid >= 256 * K) return;
        int n = tid / K;
        int k = tid - n * K;
        float v = (n < CO) ? Wl[k * CO + n] : Wr[k * CO + (n - CO)];
        WT[tid] = f2b(v);
        return;
    }
    blk -= PB_WT0 + PB_WT1 + PB_WT2;
    {
        const float* Wl; const float* Wr; const float* bias; float* iQl; float* iQr; int Ktop; int g;
        if (blk < PB_INFO) { Wl = Wl0; Wr = Wr0; bias = b0; iQl = iQl0; iQr = iQr0; Ktop = 96;  g = blk; }
        else if (blk < 2 * PB_INFO) { Wl = Wl1; Wr = Wr1; bias = b1; iQl = iQl1; iQr = iQr1; Ktop = 128; g = blk - PB_INFO; }
        else { Wl = Wl2; Wr = Wr2; bias = b2; iQl = iQl2; iQr = iQr2; Ktop = 128; g = blk - 2 * PB_INFO; }
        int c = t & 127;
        int sel = t >> 7;
        const float* W = sel ? Wr : Wl;
        float a = sel ? bias[c] : 0.0f;
        for (int d = 0; d < DI; ++d)
            a += info[g * DI + d] * W[(Ktop + d) * CO + c];
        (sel ? iQr : iQl)[g * CO + c] = a;
    }
}

// ================= binB: per-range CSR fill (single-writer csr lines, no ping-pong) =================
__global__ __launch_bounds__(256) void k_binB(const u32* __restrict__ ebin,
                                              const int* __restrict__ grescnt,
                                              int* __restrict__ cnt, u16* __restrict__ csr) {
    __shared__ int lcnt[256];
    int r = blockIdx.x;
    int t = threadIdx.x;
    lcnt[t] = 0;
    __syncthreads();
    int total = grescnt[r * 16];
    if (total > (1 << RCAPLOG)) total = 1 << RCAPLOG;
    for (int j = t; j < total; j += 256) {
        u32 p = ebin[(r << RCAPLOG) + j];
        int dloc = p >> 24;
        int rank = atomicAdd(&lcnt[dloc], 1);
        int node = (r << 8) + dloc;
        if (rank < (1 << CAPLOG)) csr[(node << CAPLOG) + rank] = (u16)(p & 0xffff);
    }
    __syncthreads();
    int node = (r << 8) + t;
    if (node < NN) cnt[node] = lcnt[t];
}

// ================= MFMA GEMM + fused combine =================
template<int K>
__global__ __launch_bounds__(256) void k_mfma(const u16* __restrict__ A,
                                              const u16* __restrict__ WTg,
                                              const int* __restrict__ batch,
                                              const float* __restrict__ iQl,
                                              const float* __restrict__ iQr,
                                              u16* __restrict__ zlp,
                                              u16* __restrict__ zq) {
    constexpr int PITCH = K + 8;
    __shared__ short lds[256 * PITCH];

    int tid  = threadIdx.x;
    int w    = tid >> 6;
    int lane = tid & 63;
    int quad = lane >> 4;
    int l15  = lane & 15;

    constexpr int CH = 256 * K / 8;
    const uint4* wp = (const uint4*)WTg;
    for (int c = tid; c < CH; c += 256) {
        int n  = c / (K / 8);
        int ko = (c - n * (K / 8)) * 8;
        *(uint4*)&lds[n * PITCH + ko] = wp[c];
    }
    __syncthreads();

    int i0 = blockIdx.x * 128 + w * 32;
    int r0 = i0 + l15;       if (r0 >= NN) r0 = NN - 1;
    int r1 = i0 + 16 + l15;  if (r1 >= NN) r1 = NN - 1;
    const short* A0 = (const short*)A + (size_t)r0 * K;
    const short* A1 = (const short*)A + (size_t)r1 * K;

    f32x4 acc[2][16];
#pragma unroll
    for (int rt = 0; rt < 2; ++rt)
#pragma unroll
        for (int ct = 0; ct < 16; ++ct)
            acc[rt][ct] = (f32x4){0.f, 0.f, 0.f, 0.f};

#pragma unroll
    for (int ks = 0; ks < K / 32; ++ks) {
        int ka = ks * 32 + quad * 8;
        bf16x8 a0 = *(const bf16x8*)(A0 + ka);
        bf16x8 a1 = *(const bf16x8*)(A1 + ka);
#pragma unroll
        for (int ct = 0; ct < 16; ++ct) {
            bf16x8 b = *(const bf16x8*)&lds[(ct * 16 + l15) * PITCH + ka];
            acc[0][ct] = __builtin_amdgcn_mfma_f32_16x16x32_bf16(a0, b, acc[0][ct], 0, 0, 0);
            acc[1][ct] = __builtin_amdgcn_mfma_f32_16x16x32_bf16(a1, b, acc[1][ct], 0, 0, 0);
        }
    }

#pragma unroll
    for (int rt = 0; rt < 2; ++rt) {
#pragma unroll
        for (int reg = 0; reg < 4; ++reg) {
            int row = i0 + rt * 16 + quad * 4 + reg;
            if (row < NN) {
                int b = batch[row];
                const float* ql = &iQl[b * CO];
                const float* qr = &iQr[b * CO];
                u16* lp = zlp + (size_t)row * CO;
                u16* qp = zq  + (size_t)row * CO;
#pragma unroll
                for (int ct = 0; ct < 8; ++ct) {
                    int col = ct * 16 + l15;
                    lp[col] = f2b(acc[rt][ct][reg] + ql[col]);
                }
#pragma unroll
                for (int ct = 8; ct < 16; ++ct) {
                    int col = ct * 16 + l15 - 128;
                    qp[col] = f2b(acc[rt][ct][reg] + qr[col]);
                }
            }
        }
    }
}

// ================= gather-mean: h = mean(zlp[nbrs]) + zq =================
__device__ __forceinline__ void acc8(float* a, const uint4& u) {
    a[0] += blo(u.x); a[1] += bhi(u.x);
    a[2] += blo(u.y); a[3] += bhi(u.y);
    a[4] += blo(u.z); a[5] += bhi(u.z);
    a[6] += blo(u.w); a[7] += bhi(u.w);
}

__global__ __launch_bounds__(256) void k_gatherb(const u32* __restrict__ zlp, const u32* __restrict__ zq,
                                                 const int* __restrict__ cnt, const u16* __restrict__ csr,
                                                 u32* __restrict__ hout) {
    int wave = threadIdx.x >> 6;
    int lane = threadIdx.x & 63;
    int q    = lane >> 4;       // quarter 0..3
    int l16  = lane & 15;
    int i = blockIdx.x * 4 + wave;
    if (i >= NN) return;
    int deg = cnt[i];
    int degc = min(deg, 1 << CAPLOG);
    int s0 = i << CAPLOG;
    int s1 = s0 + degc;

    const uint4* Z = (const uint4*)zlp;

    float a[8] = {0,0,0,0,0,0,0,0};
    float b[8] = {0,0,0,0,0,0,0,0};
    float c[8] = {0,0,0,0,0,0,0,0};
    float d[8] = {0,0,0,0,0,0,0,0};

    int e = s0;
    for (; e + 15 < s1; e += 16) {
        int n0 = csr[e + q];
        int n1 = csr[e + 4 + q];
        int n2 = csr[e + 8 + q];
        int n3 = csr[e + 12 + q];
        uint4 u0 = Z[(size_t)n0 * 16 + l16];
        uint4 u1 = Z[(size_t)n1 * 16 + l16];
        uint4 u2 = Z[(size_t)n2 * 16 + l16];
        uint4 u3 = Z[(size_t)n3 * 16 + l16];
        acc8(a, u0); acc8(b, u1); acc8(c, u2); acc8(d, u3);
    }
    for (; e < s1; e += 4) {
        if (e + q < s1) {
            int n0 = csr[e + q];
            uint4 u0 = Z[(size_t)n0 * 16 + l16];
            acc8(a, u0);
        }
    }
#pragma unroll
    for (int j = 0; j < 8; ++j) {
        a[j] += b[j] + c[j] + d[j];
        a[j] += __shfl_xor(a[j], 16);
        a[j] += __shfl_xor(a[j], 32);
    }
    if (q == 0) {
        float r = 1.0f / fmaxf((float)deg, 1.0f);
        uint4 qq = ((const uint4*)zq)[(size_t)i * 16 + l16];
        uint4 o;
        o.x = (u32)f2b(a[0] * r + blo(qq.x)) | ((u32)f2b(a[1] * r + bhi(qq.x)) << 16);
        o.y = (u32)f2b(a[2] * r + blo(qq.y)) | ((u32)f2b(a[3] * r + bhi(qq.y)) << 16);
        o.z = (u32)f2b(a[4] * r + blo(qq.z)) | ((u32)f2b(a[5] * r + bhi(qq.z)) << 16);
        o.w = (u32)f2b(a[6] * r + blo(qq.w)) | ((u32)f2b(a[7] * r + bhi(qq.w)) << 16);
        ((uint4*)hout)[(size_t)i * 16 + l16] = o;
    }
}

// ================= fused pool + FC head =================
__global__ __launch_bounds__(384) void k_poolfc(const u32* __restrict__ h1, const u32* __restrict__ h2,
                                                const u32* __restrict__ h3, const int* __restrict__ start,
                                                const float* __restrict__ W1, const float* __restrict__ b1,
                                                const float* __restrict__ W2, const float* __restrict__ b2,
                                                float* __restrict__ out) {
    __shared__ float s_part[6][128];
    __shared__ float s_g[F1I];
    __shared__ float s_z[F1O];
    int gr = blockIdx.x;
    int t  = threadIdx.x;
    int w    = t >> 6;
    int lane = t & 63;
    int buf  = w % 3;
    int half = w / 3;
    const u32* hb = (buf == 0) ? h1 : (buf == 1) ? h2 : h3;
    int s = start[gr], e = start[gr + 1];
    int mid = (s + e) >> 1;
    int n0 = half ? mid : s;
    int n1 = half ? e : mid;

    float mlo[4], mhi[4];
#pragma unroll
    for (int j = 0; j < 4; ++j) { mlo[j] = -FLT_MAX; mhi[j] = -FLT_MAX; }
    int n = n0;
    for (; n + 3 < n1; n += 4) {
        u32 v0 = hb[(size_t)(n + 0) * 64 + lane];
        u32 v1 = hb[(size_t)(n + 1) * 64 + lane];
        u32 v2 = hb[(size_t)(n + 2) * 64 + lane];
        u32 v3 = hb[(size_t)(n + 3) * 64 + lane];
        mlo[0] = fmaxf(mlo[0], blo(v0)); mhi[0] = fmaxf(mhi[0], bhi(v0));
        mlo[1] = fmaxf(mlo[1], blo(v1)); mhi[1] = fmaxf(mhi[1], bhi(v1));
        mlo[2] = fmaxf(mlo[2], blo(v2)); mhi[2] = fmaxf(mhi[2], bhi(v2));
        mlo[3] = fmaxf(mlo[3], blo(v3)); mhi[3] = fmaxf(mhi[3], bhi(v3));
    }
    for (; n < n1; ++n) {
        u32 v0 = hb[(size_t)n * 64 + lane];
        mlo[0] = fmaxf(mlo[0], blo(v0)); mhi[0] = fmaxf(mhi[0], bhi(v0));
    }
    float lo = fmaxf(fmaxf(mlo[0], mlo[1]), fmaxf(mlo[2], mlo[3]));
    float hi = fmaxf(fmaxf(mhi[0], mhi[1]), fmaxf(mhi[2], mhi[3]));
    s_part[w][2 * lane]     = lo;
    s_part[w][2 * lane + 1] = hi;
    __syncthreads();
    {
        int buf2 = t >> 7, cc = t & 127;
        s_g[t] = fmaxf(s_part[buf2][cc], s_part[buf2 + 3][cc]);
    }
    __syncthreads();
    if (t < F1O) {
        float acc = b1[t];
        for (int k = 0; k < F1I; ++k) acc += s_g[k] * W1[k * F1O + t];
        s_z[t] = fmaxf(acc, 0.0f);
    }
    __syncthreads();
    if (t < F2O) {
        float a = b2[t];
        for (int k = 0; k < F1O; ++k) a += s_z[k] * W2[k * F2O + t];
        out[gr * F2O + t] = a;
    }
}

extern "C" void kernel_launch(void* const* d_in, const int* in_sizes, int n_in,
                              void* d_out, int out_size, void* d_ws, size_t ws_size,
                              hipStream_t stream) {
    const float* x     = (const float*)d_in[0];
    const int*   eidx  = (const int*)d_in[1];
    const int*   batch = (const int*)d_in[2];
    const float* info  = (const float*)d_in[3];
    const float* Wl0 = (const float*)d_in[4];
    const float* Wr0 = (const float*)d_in[5];
    const float* b0  = (const float*)d_in[6];
    const float* Wl1 = (const float*)d_in[7];
    const float* Wr1 = (const float*)d_in[8];
    const float* b1  = (const float*)d_in[9];
    const float* Wl2 = (const float*)d_in[10];
    const float* Wr2 = (const float*)d_in[11];
    const float* b2  = (const float*)d_in[12];
    const float* Wfc1  = (const float*)d_in[13];
    const float* bfc1  = (const float*)d_in[14];
    const float* Wfc2  = (const float*)d_in[15];
    const float* bfc2  = (const float*)d_in[16];
    float* out = (float*)d_out;

    const int* src = eidx;
    const int* dst = eidx + NE;

    // workspace layout (byte offsets, 16B-aligned)
    char* W = (char*)d_ws;
    u16* xb     = (u16*)(W + 0);             // 50000*96 bf16
    u16* h1     = (u16*)(W + 9600000);       // 50000*128 bf16 each
    u16* h2     = (u16*)(W + 22400000);
    u16* h3     = (u16*)(W + 35200000);
    u16* zlp    = (u16*)(W + 48000000);      // 50000*128 bf16
    u16* zq     = (u16*)(W + 60800000);
    u16* WT0    = (u16*)(W + 73600000);      // 256*96
    u16* WT1    = (u16*)(W + 73649152);      // 256*128
    u16* WT2    = (u16*)(W + 73714688);
    float* iQl0 = (float*)(W + 73780224);    // 500*128 f32 each
    float* iQr0 = (float*)(W + 74036224);
    float* iQl1 = (float*)(W + 74292224);
    float* iQr1 = (float*)(W + 74548224);
    float* iQl2 = (float*)(W + 74804224);
    float* iQr2 = (float*)(W + 75060224);
    int* start  = (int*)(W + 75316224);      // NG+1
    int* cnt    = (int*)(W + 75318272);      // NN
    u16* csr    = (u16*)(W + 75518336);      // NN*128 u16 buckets = 12.8 MB
    u32* ebin   = (u32*)(W + 88318336);      // 256 ranges * 8192 * u32 = 8 MB
    int* grescnt= (int*)(W + 96706560);      // 256 padded counters (x16 ints)

    // ---- zero reservation counters (16 KB) ----
    hipMemsetAsync(grescnt, 0, 256 * 16 * sizeof(int), stream);

    // ---- fused prep: binA | starts | cast | wt | infow ----
    k_prep<<<PREP_GRID, 256, 0, stream>>>(x, batch, info, src, dst,
        Wl0, Wr0, b0, Wl1, Wr1, b1, Wl2, Wr2, b2,
        grescnt, ebin, start, xb, WT0, WT1, WT2, iQl0, iQr0, iQl1, iQr1, iQl2, iQr2);

    // ---- binB: per-range CSR fill + cnt writeback ----
    k_binB<<<NRANGE, 256, 0, stream>>>(ebin, grescnt, cnt, csr);

    const int gGemm = (NN + 127) / 128;
    const int gGath = (NN + 3) / 4;

    // ---- layer 0 ----
    k_mfma<96><<<gGemm, 256, 0, stream>>>(xb, WT0, batch, iQl0, iQr0, zlp, zq);
    k_gatherb<<<gGath, 256, 0, stream>>>((const u32*)zlp, (const u32*)zq, cnt, csr, (u32*)h1);

    // ---- layer 1 ----
    k_mfma<128><<<gGemm, 256, 0, stream>>>(h1, WT1, batch, iQl1, iQr1, zlp, zq);
    k_gatherb<<<gGath, 256, 0, stream>>>((const u32*)zlp, (const u32*)zq, cnt, csr, (u32*)h2);

    // ---- layer 2 ----
    k_mfma<128><<<gGemm, 256, 0, stream>>>(h2, WT2, batch, iQl2, iQr2, zlp, zq);
    k_gatherb<<<gGath, 256, 0, stream>>>((const u32*)zlp, (const u32*)zq, cnt, csr, (u32*)h3);

    // ---- fused pool + head ----
    k_poolfc<<<NG, 384, 0, stream>>>((const u32*)h1, (const u32*)h2, (const u32*)h3, start,
                                     Wfc1, bfc1, Wfc2, bfc2, out);
}